// Round 11
// baseline (143.008 us; speedup 1.0000x reference)
//
#include <hip/hip_runtime.h>
#include <hip/hip_bf16.h>

typedef __attribute__((ext_vector_type(8))) short bf16x8;
typedef __attribute__((ext_vector_type(4))) float f32x4;
typedef __attribute__((ext_vector_type(4))) short short4v;
typedef unsigned short ushort_t;

#define CC 120
#define LL 469
#define HH 64

constexpr int NBATCH = 1024;           // (s,b) pairs; raw reshape => batch contiguous
constexpr int KSTEPS = (LL + 31) / 32; // 15

// ---- LDS layout ----
// phase 1: Xf[2][4 waves][32 rows][32 k] f32 = 32768 B, per-wave private -> NO barriers.
//          W never touches LDS (fragment image -> registers, macro-generated, no pointers).
// phase 2: Qb @0 (16 KB, [128]x128B swz), Kb @16384, Vb @32768 ([64]x256B swz)
//          Pb @0 (32 KB) aliases Q+K after QK^T barrier; epilogue Ob f32 [120][68] @0
constexpr int XBUF_DW    = 128 * 32;              // 4096 dwords per buffer
constexpr int SMEM_BYTES = 49152;                 // phase2 needs 48K (> 32K phase1)
constexpr int WIMG_SHORTS = KSTEPS * 12 * 64 * 8; // 92160
constexpr int WIMG_BYTES  = WIMG_SHORTS * 2;      // 184320

__device__ __forceinline__ ushort_t f2bf(float f) {
  __hip_bfloat16 h = __float2bfloat16(f);
  return __builtin_bit_cast(ushort_t, h);
}

__device__ __forceinline__ void gload_lds4(const void* g, void* l) {
  __builtin_amdgcn_global_load_lds(
      (const __attribute__((address_space(1))) unsigned int*)g,
      (__attribute__((address_space(3))) unsigned int*)l, 4, 0, 0);
}

// XOR-swizzled LDS address for phase-2 tiles
__device__ __forceinline__ char* sptr(char* base, int row, int stride, int byteoff) {
  return base + row * stride + (byteoff ^ ((row & 7) << 4));
}

// W image in MFMA fragment order:
// wimg[((t*12+n)*64+lane)*8+j] = Wcat[t*32+(lane>>4)*8+j][n*16+(lane&15)], 0 for k>=LL
__global__ void prep_w(const float* __restrict__ Wk, const float* __restrict__ Wq,
                       const float* __restrict__ Wv, ushort_t* __restrict__ wimg) {
  int idx = blockIdx.x * 256 + threadIdx.x; // 92160 exactly (360 blocks)
  int j = idx & 7;
  int lane = (idx >> 3) & 63;
  int tn = idx >> 9;
  int n = tn % 12;
  int t = tn / 12;
  int lr = lane & 15, lg = lane >> 4;
  int k = t * 32 + lg * 8 + j;
  int col = n * 16 + lr;
  int wsel = col >> 6, h = col & 63;
  const float* wp = (wsel == 0) ? Wk : (wsel == 1) ? Wq : Wv;
  float v = (k < LL) ? wp[(size_t)k * HH + h] : 0.f;
  wimg[idx] = f2bf(v);
}

// W fragment loads: 12 coalesced dwordx4 (1 KB each), constant-indexed array writes.
#define WLOAD(T, WF)                                                          \
  {                                                                           \
    const ushort_t* _src = wimg + (size_t)(T) * 6144 + (size_t)lane * 8;      \
    _Pragma("unroll")                                                         \
    for (int _n = 0; _n < 12; ++_n)                                           \
      WF[_n] = *(const bf16x8*)(_src + _n * 512);                             \
  }

// compute step T from per-wave LDS X tile + W fragments (constant-indexed only)
#define COMPUTE(T, WF)                                                        \
  {                                                                           \
    const float* _xb = Xf + ((T) & 1) * XBUF_DW + wv * 1024;                  \
    f32x4 _c00 = *(const f32x4*)(_xb + lr * 32 + (((lg * 2) ^ (lr & 7)) << 2));       \
    f32x4 _c01 = *(const f32x4*)(_xb + lr * 32 + (((lg * 2 + 1) ^ (lr & 7)) << 2));   \
    f32x4 _c10 = *(const f32x4*)(_xb + (16 + lr) * 32 + (((lg * 2) ^ (lr & 7)) << 2));\
    f32x4 _c11 = *(const f32x4*)(_xb + (16 + lr) * 32 + (((lg * 2 + 1) ^ (lr & 7)) << 2)); \
    bf16x8 _a0, _a1;                                                          \
    _Pragma("unroll")                                                         \
    for (int _j = 0; _j < 4; ++_j) {                                          \
      _a0[_j] = (short)f2bf(_c00[_j]); _a0[4 + _j] = (short)f2bf(_c01[_j]);   \
      _a1[_j] = (short)f2bf(_c10[_j]); _a1[4 + _j] = (short)f2bf(_c11[_j]);   \
    }                                                                         \
    _Pragma("unroll")                                                         \
    for (int _n = 0; _n < 12; ++_n) {                                         \
      acc[0][_n] = __builtin_amdgcn_mfma_f32_16x16x32_bf16(_a0, WF[_n], acc[0][_n], 0, 0, 0); \
      acc[1][_n] = __builtin_amdgcn_mfma_f32_16x16x32_bf16(_a1, WF[_n], acc[1][_n], 0, 0, 0); \
    }                                                                         \
  }

template <bool WIMG>
__global__ __launch_bounds__(256, 2)
void fused_regional_head(const float* __restrict__ x,
                         const float* __restrict__ Wk,
                         const float* __restrict__ Wq,
                         const float* __restrict__ Wv,
                         const ushort_t* __restrict__ wimg,
                         float* __restrict__ out) {
  __shared__ char smem[SMEM_BYTES];
  const int tid = threadIdx.x;
  const int lane = tid & 63;
  const int wv = tid >> 6;   // wave 0..3, owns rows 32*wv .. 32*wv+31
  const int lr = lane & 15;
  const int lg = lane >> 4;
  const int batch = blockIdx.x;
  const size_t xbase = (size_t)batch * CC * LL;

  float* Xf = (float*)smem; // [2][128][32] f32; wave w owns dwords w*1024..+1023

  // Per-wave X staging: 16 gload_lds4 (15 rows*... 32 rows x 32 dw = 1024 dw).
  // LDS linear; global source chunk-XOR swizzled. Rows>=CC / k>=LL clamped
  // (garbage masked downstream: softmax col-mask + epilogue row guard + P zeros).
  auto stage_x = [&](int t) {
    float* dst = Xf + (t & 1) * XBUF_DW + wv * 1024;
    const int k0 = t * 32;
#pragma unroll
    for (int i = 0; i < 16; ++i) {
      int dwl = i * 64 + lane;          // 0..1023
      int rl = dwl >> 5;                // local row 0..31
      int w = dwl & 31;
      int lw = (((w >> 2) ^ (rl & 7)) << 2) | (w & 3);
      int row = wv * 32 + rl;
      int rowc = (row < CC) ? row : (CC - 1);
      int k = k0 + lw;
      int kc = (k < LL) ? k : (LL - 1);
      gload_lds4(x + xbase + (size_t)rowc * LL + kc, dst + i * 64);
    }
  };

  // ---------------- phase 1: QKV = X @ [Wk|Wq|Wv], barrier-free ----------------
  f32x4 acc[2][12];
#pragma unroll
  for (int m = 0; m < 2; ++m)
#pragma unroll
    for (int n = 0; n < 12; ++n) acc[m][n] = (f32x4){0.f, 0.f, 0.f, 0.f};

  if constexpr (WIMG) {
    bf16x8 wfA[12], wfB[12];
    stage_x(0);
    WLOAD(0, wfA);
#pragma unroll
    for (int tt = 0; tt < 7; ++tt) {
      const int t = tt * 2;
      stage_x(t + 1);
      WLOAD(t + 1, wfB);                 // 15+12 = 27 issued this step
      __builtin_amdgcn_sched_barrier(0);
      asm volatile("s_waitcnt vmcnt(27)" ::: "memory"); // drain step t's 27
      __builtin_amdgcn_sched_barrier(0);
      COMPUTE(t, wfA);
      if (t + 2 < KSTEPS) {
        stage_x(t + 2);
        WLOAD(t + 2, wfA);
        __builtin_amdgcn_sched_barrier(0);
        asm volatile("s_waitcnt vmcnt(27)" ::: "memory");
      } else {
        asm volatile("s_waitcnt vmcnt(0)" ::: "memory");
      }
      __builtin_amdgcn_sched_barrier(0);
      COMPUTE(t + 1, wfB);
    }
    asm volatile("s_waitcnt vmcnt(0)" ::: "memory"); // drain step 14
    __builtin_amdgcn_sched_barrier(0);
    COMPUTE(14, wfA);
  } else {
    // slow fallback (unused when ws present)
    for (int t = 0; t < KSTEPS; ++t) {
      stage_x(t);
      bf16x8 wf[12];
#pragma unroll
      for (int n = 0; n < 12; ++n) {
        int col = n * 16 + lr;
        int wsel = col >> 6, h = col & 63;
        const float* wp = (wsel == 0) ? Wk : (wsel == 1) ? Wq : Wv;
#pragma unroll
        for (int j = 0; j < 8; ++j) {
          int k = t * 32 + lg * 8 + j;
          wf[n][j] = (short)f2bf((k < LL) ? wp[(size_t)k * HH + h] : 0.f);
        }
      }
      asm volatile("s_waitcnt vmcnt(0)" ::: "memory");
      __builtin_amdgcn_sched_barrier(0);
      COMPUTE(t, wf);
    }
  }
  __syncthreads(); // all waves done with Xf; phase-2 tiles take over

  // ---------------- write Q,K,V (bf16, swizzled) ----------------
  char* Qb = smem;
  char* Kb = smem + 16384;
  char* Vb = smem + 32768;
  char* Pb = smem;
#pragma unroll
  for (int mt = 0; mt < 2; ++mt) {
#pragma unroll
    for (int r = 0; r < 4; ++r) {
      int row = wv * 32 + mt * 16 + lg * 4 + r;
#pragma unroll
      for (int n = 0; n < 4; ++n) {
        *(ushort_t*)sptr(Kb, row, 128, (n * 16 + lr) * 2) = f2bf(acc[mt][n][r]);
        *(ushort_t*)sptr(Qb, row, 128, (n * 16 + lr) * 2) = f2bf(acc[mt][4 + n][r]);
      }
    }
    // V^T packed: 4 consecutive d-rows -> ds_write_b64
#pragma unroll
    for (int n = 0; n < 4; ++n) {
      short4v pk;
#pragma unroll
      for (int r = 0; r < 4; ++r) pk[r] = (short)f2bf(acc[mt][8 + n][r]);
      *(short4v*)sptr(Vb, n * 16 + lr, 256, (wv * 32 + mt * 16 + lg * 4) * 2) = pk;
    }
  }
  __syncthreads();

  // ---------------- QK^T ----------------
  f32x4 accw[2][8];
#pragma unroll
  for (int m = 0; m < 2; ++m)
#pragma unroll
    for (int n = 0; n < 8; ++n) accw[m][n] = (f32x4){0.f, 0.f, 0.f, 0.f};
#pragma unroll
  for (int ks = 0; ks < 2; ++ks) {
    bf16x8 a0 = *(const bf16x8*)sptr(Qb, wv * 32 + lr, 128, ks * 64 + lg * 16);
    bf16x8 a1 = *(const bf16x8*)sptr(Qb, wv * 32 + 16 + lr, 128, ks * 64 + lg * 16);
#pragma unroll
    for (int n = 0; n < 8; ++n) {
      bf16x8 b = *(const bf16x8*)sptr(Kb, n * 16 + lr, 128, ks * 64 + lg * 16);
      accw[0][n] = __builtin_amdgcn_mfma_f32_16x16x32_bf16(a0, b, accw[0][n], 0, 0, 0);
      accw[1][n] = __builtin_amdgcn_mfma_f32_16x16x32_bf16(a1, b, accw[1][n], 0, 0, 0);
    }
  }
  __syncthreads(); // all done reading Q/K before P overwrites

  // ---------------- softmax (wave-parallel over 16-lane col groups) ----------------
#pragma unroll
  for (int mt = 0; mt < 2; ++mt)
#pragma unroll
    for (int r = 0; r < 4; ++r) {
      float l[8];
      float m = -1e30f;
#pragma unroll
      for (int n = 0; n < 8; ++n) {
        float v = accw[mt][n][r] * 0.125f;
        if (n == 7 && lr >= 8) v = -1e30f; // col = 112+lr >= 120 masked
        l[n] = v;
        m = fmaxf(m, v);
      }
#pragma unroll
      for (int off = 1; off < 16; off <<= 1) m = fmaxf(m, __shfl_xor(m, off));
      float s = 0.f;
#pragma unroll
      for (int n = 0; n < 8; ++n) {
        float p = __expf(l[n] - m);
        l[n] = p;
        s += p;
      }
#pragma unroll
      for (int off = 1; off < 16; off <<= 1) s += __shfl_xor(s, off);
      float inv = 1.f / s;
      int row = wv * 32 + mt * 16 + lg * 4 + r;
#pragma unroll
      for (int n = 0; n < 8; ++n)
        *(ushort_t*)sptr(Pb, row, 256, (n * 16 + lr) * 2) = f2bf(l[n] * inv);
    }
  // no barrier: each wave reads only its own P rows; V covered by barrier above

  // ---------------- out = P @ V ----------------
  f32x4 acco[2][4];
#pragma unroll
  for (int m = 0; m < 2; ++m)
#pragma unroll
    for (int n = 0; n < 4; ++n) acco[m][n] = (f32x4){0.f, 0.f, 0.f, 0.f};
#pragma unroll
  for (int ks = 0; ks < 4; ++ks) {
    bf16x8 a0 = *(const bf16x8*)sptr(Pb, wv * 32 + lr, 256, ks * 64 + lg * 16);
    bf16x8 a1 = *(const bf16x8*)sptr(Pb, wv * 32 + 16 + lr, 256, ks * 64 + lg * 16);
#pragma unroll
    for (int n = 0; n < 4; ++n) {
      bf16x8 b = *(const bf16x8*)sptr(Vb, n * 16 + lr, 256, ks * 64 + lg * 16);
      acco[0][n] = __builtin_amdgcn_mfma_f32_16x16x32_bf16(a0, b, acco[0][n], 0, 0, 0);
      acco[1][n] = __builtin_amdgcn_mfma_f32_16x16x32_bf16(a1, b, acco[1][n], 0, 0, 0);
    }
  }

  // ---------------- epilogue: LDS transpose -> float4 coalesced stores ----------------
  __syncthreads(); // P/V dead
  float* Ob = (float*)smem; // [120][68] f32
#pragma unroll
  for (int mt = 0; mt < 2; ++mt)
#pragma unroll
    for (int r = 0; r < 4; ++r) {
      int row = wv * 32 + mt * 16 + lg * 4 + r;
      if (row < CC) {
#pragma unroll
        for (int n = 0; n < 4; ++n)
          Ob[row * 68 + n * 16 + lr] = acco[mt][n][r];
      }
    }
  __syncthreads();
  const size_t obase = (size_t)batch * CC * HH;
#pragma unroll
  for (int i = 0; i < 8; ++i) {
    int idx = i * 256 + tid; // float4 index, 1920 total
    if (idx < 1920) {
      int row = idx >> 4;
      int c4 = (idx & 15) * 4;
      f32x4 v = *(const f32x4*)(Ob + row * 68 + c4);
      *(f32x4*)(out + obase + (size_t)idx * 4) = v;
    }
  }
}

extern "C" void kernel_launch(void* const* d_in, const int* in_sizes, int n_in,
                              void* d_out, int out_size, void* d_ws, size_t ws_size,
                              hipStream_t stream) {
  (void)in_sizes; (void)n_in; (void)out_size;
  const float* x  = (const float*)d_in[0];
  const float* Wk = (const float*)d_in[1];
  const float* Wq = (const float*)d_in[2];
  const float* Wv = (const float*)d_in[3];
  float* out = (float*)d_out;
  if (ws_size >= (size_t)WIMG_BYTES && d_ws != nullptr) {
    ushort_t* wimg = (ushort_t*)d_ws;
    prep_w<<<360, 256, 0, stream>>>(Wk, Wq, Wv, wimg);
    fused_regional_head<true><<<NBATCH, 256, 0, stream>>>(x, Wk, Wq, Wv, wimg, out);
  } else {
    fused_regional_head<false><<<NBATCH, 256, 0, stream>>>(x, Wk, Wq, Wv, nullptr, out);
  }
}

// Round 12
// 102.606 us; speedup vs baseline: 1.3938x; 1.3938x over previous
//
#include <hip/hip_runtime.h>
#include <hip/hip_bf16.h>

typedef __attribute__((ext_vector_type(8))) short bf16x8;
typedef __attribute__((ext_vector_type(4))) float f32x4;
typedef __attribute__((ext_vector_type(4))) short short4v;
typedef unsigned short ushort_t;

#define CC 120
#define LL 469
#define HH 64

constexpr int NBATCH = 1024;           // (s,b) pairs; raw reshape => batch contiguous
constexpr int KSTEPS = (LL + 31) / 32; // 15

// ---- LDS layout ----
// phase 1: Xf[2][120][32] f32 @0 (30720 B, source-chunk-XOR swizzled, double-buffered DMA),
//          Wl[8192 shorts] @30720 (16384 B; SINGLE buffer, 15 live 1KB chunks + 1 pad)
//          -> 47104 B; SMEM 49152 => 3 blocks/CU (was 2 at 63.5K)
// phase 2: Qb @0 (16 KB, [128]x128B swz), Kb @16384, Vb @32768 ([64]x256B swz)
//          Pb @0 (32 KB) aliases Q+K after QK^T barrier; epilogue Ob f32 [120][68] @0
constexpr int XBUF_FLOATS = 120 * 32;              // 3840 dwords = 15/thread
constexpr int X_BYTES     = 2 * XBUF_FLOATS * 4;   // 30720
constexpr int WB_SHORTS   = 8192;                  // 16 KB single W buffer (padded)
constexpr int SMEM_BYTES  = 49152;                 // phase2 needs 48K
constexpr int WIMG_SHORTS = KSTEPS * WB_SHORTS;    // 122880
constexpr int WIMG_BYTES  = WIMG_SHORTS * 2;       // 245760

__device__ __forceinline__ ushort_t f2bf(float f) {
  __hip_bfloat16 h = __float2bfloat16(f);
  return __builtin_bit_cast(ushort_t, h);
}

__device__ __forceinline__ void gload_lds4(const void* g, void* l) {
  __builtin_amdgcn_global_load_lds(
      (const __attribute__((address_space(1))) unsigned int*)g,
      (__attribute__((address_space(3))) unsigned int*)l, 4, 0, 0);
}
__device__ __forceinline__ void gload_lds16(const void* g, void* l) {
  __builtin_amdgcn_global_load_lds(
      (const __attribute__((address_space(1))) unsigned int*)g,
      (__attribute__((address_space(3))) unsigned int*)l, 16, 0, 0);
}

// XOR-swizzled LDS address for phase-2 tiles
__device__ __forceinline__ char* sptr(char* base, int row, int stride, int byteoff) {
  return base + row * stride + (byteoff ^ ((row & 7) << 4));
}

// W image: per step t a 16 KB block; first 15360 B = [192 cols][40 k] bf16, rest pad.
__global__ void prep_w(const float* __restrict__ Wk, const float* __restrict__ Wq,
                       const float* __restrict__ Wv, ushort_t* __restrict__ wimg) {
  int idx = blockIdx.x * 256 + threadIdx.x; // 122880 exactly (480 blocks)
  int t = idx / WB_SHORTS;
  int r = idx % WB_SHORTS;
  int col = r / 40, kk = r % 40;
  float v = 0.f;
  if (r < 192 * 40 && kk < 32) {
    int k = t * 32 + kk;
    int wsel = col >> 6, h = col & 63;
    const float* wp = (wsel == 0) ? Wk : (wsel == 1) ? Wq : Wv;
    if (k < LL) v = wp[(size_t)k * HH + h];
  }
  wimg[idx] = f2bf(v);
}

template <bool WIMG>
__global__ __launch_bounds__(256, 3)
void fused_regional_head(const float* __restrict__ x,
                         const float* __restrict__ Wk,
                         const float* __restrict__ Wq,
                         const float* __restrict__ Wv,
                         const ushort_t* __restrict__ wimg,
                         float* __restrict__ out) {
  __shared__ char smem[SMEM_BYTES];
  const int tid = threadIdx.x;
  const int lane = tid & 63;
  const int wv = tid >> 6;   // wave 0..3, owns rows 32*wv .. 32*wv+31
  const int lr = lane & 15;
  const int lg = lane >> 4;
  const int batch = blockIdx.x;
  const size_t xbase = (size_t)batch * CC * LL;

  float* Xf = (float*)smem;                       // [2][120][32] f32, chunk-swizzled
  ushort_t* Wl = (ushort_t*)(smem + X_BYTES);     // [8192] shorts, single buffer

  // X stage: 15 gload_lds4 per thread. LDS linear; global source chunk-XOR
  // swizzled so ds_read of logical 16B chunk s reads phys s^(row&7).
  auto stage_x = [&](int t) {
    float* dst = Xf + (t & 1) * XBUF_FLOATS;
    const int k0 = t * 32;
    const bool tail = (t == KSTEPS - 1);
#pragma unroll
    for (int i = 0; i < 15; ++i) {
      int slot = i * 4 + wv;              // 0..59, wave-uniform
      int dw = slot * 64 + lane;          // dword in [0,3840)
      int row = dw >> 5;
      int w = dw & 31;
      int lw = (((w >> 2) ^ (row & 7)) << 2) | (w & 3); // logical k-word
      int k = k0 + lw;
      if (tail) {
        if (k >= LL) dst[dw] = 0.f;       // zero invalid (drained by lgkmcnt at barriers)
        if (k < LL) gload_lds4(x + xbase + (size_t)row * LL + k, dst + slot * 64);
      } else {
        gload_lds4(x + xbase + (size_t)row * LL + k, dst + slot * 64);
      }
    }
  };
  // W stage: exactly 4 gload_lds16 per thread (16 chunks of 1 KB incl. pad chunk)
  auto stage_w_fast = [&](int t) {
    const char* src = (const char*)(wimg + (size_t)t * WB_SHORTS);
    char* dst = (char*)Wl;
#pragma unroll
    for (int i = 0; i < 4; ++i) {
      int c = wv + 4 * i; // 0..15, uniform
      gload_lds16(src + c * 1024 + lane * 16, dst + c * 1024);
    }
  };
  auto stage_w_slow = [&](int t) {
    const int k0 = t * 32;
#pragma unroll
    for (int j = 0; j < 24; ++j) {
      int idx = j * 256 + tid;
      int col = idx >> 5, kk = idx & 31;
      int k = k0 + kk;
      int wsel = col >> 6, h = col & 63;
      const float* wp = (wsel == 0) ? Wk : (wsel == 1) ? Wq : Wv;
      float v = (k < LL) ? wp[(size_t)k * HH + h] : 0.f;
      Wl[col * 40 + kk] = f2bf(v);
    }
  };

  // ---------------- phase 1: QKV = X @ [Wk|Wq|Wv] ----------------
  f32x4 acc[2][12];
#pragma unroll
  for (int m = 0; m < 2; ++m)
#pragma unroll
    for (int n = 0; n < 12; ++n) acc[m][n] = (f32x4){0.f, 0.f, 0.f, 0.f};

  const int row0 = wv * 32 + lr;      // < 120 always
  const int row1 = wv * 32 + 16 + lr; // >= 120 for wave3, lr>=8
  const bool r1ok = row1 < CC;

  auto compute = [&](int t) {
    const float* xb = Xf + (t & 1) * XBUF_FLOATS;
    f32x4 z = (f32x4){0.f, 0.f, 0.f, 0.f};
    f32x4 c00 = *(const f32x4*)(xb + row0 * 32 + (((lg * 2) ^ (row0 & 7)) << 2));
    f32x4 c01 = *(const f32x4*)(xb + row0 * 32 + (((lg * 2 + 1) ^ (row0 & 7)) << 2));
    f32x4 c10 = r1ok ? *(const f32x4*)(xb + row1 * 32 + (((lg * 2) ^ (row1 & 7)) << 2)) : z;
    f32x4 c11 = r1ok ? *(const f32x4*)(xb + row1 * 32 + (((lg * 2 + 1) ^ (row1 & 7)) << 2)) : z;
    bf16x8 a0, a1;
#pragma unroll
    for (int j = 0; j < 4; ++j) {
      a0[j] = (short)f2bf(c00[j]); a0[4 + j] = (short)f2bf(c01[j]);
      a1[j] = (short)f2bf(c10[j]); a1[4 + j] = (short)f2bf(c11[j]);
    }
#pragma unroll
    for (int n = 0; n < 12; ++n) {
      bf16x8 b = *(const bf16x8*)(Wl + (n * 16 + lr) * 40 + lg * 8);
      acc[0][n] = __builtin_amdgcn_mfma_f32_16x16x32_bf16(a0, b, acc[0][n], 0, 0, 0);
      acc[1][n] = __builtin_amdgcn_mfma_f32_16x16x32_bf16(a1, b, acc[1][n], 0, 0, 0);
    }
  };

  if constexpr (WIMG) {
    // prologue: X(0)+W(0), full drain
    stage_x(0);
    stage_w_fast(0);
    asm volatile("s_waitcnt vmcnt(0) lgkmcnt(0)" ::: "memory");
    __builtin_amdgcn_s_barrier();
    __builtin_amdgcn_sched_barrier(0);
    for (int t = 0; t < KSTEPS; ++t) {
      // X(t+1) first: gets the whole step as latency cover (other buffer, safe)
      if (t + 1 < KSTEPS) stage_x(t + 1);
      compute(t); // MFMA consumption forces all ds_reads of W/X(t) to return
      // barrier #1: every wave done reading Wl -> safe to overwrite
      asm volatile("s_waitcnt lgkmcnt(0)" ::: "memory");
      __builtin_amdgcn_sched_barrier(0);
      __builtin_amdgcn_s_barrier();
      if (t + 1 < KSTEPS) stage_w_fast(t + 1); // exposed ~L2 latency; occupancy absorbs
      asm volatile("s_waitcnt vmcnt(0) lgkmcnt(0)" ::: "memory");
      __builtin_amdgcn_sched_barrier(0);
      __builtin_amdgcn_s_barrier(); // barrier #2: X(t+1)+W(t+1) visible to all waves
      __builtin_amdgcn_sched_barrier(0);
    }
  } else {
    stage_x(0);
    stage_w_slow(0);
    __syncthreads();
    for (int t = 0; t < KSTEPS; ++t) {
      if (t + 1 < KSTEPS) stage_x(t + 1);
      compute(t);
      __syncthreads();
      if (t + 1 < KSTEPS) {
        stage_w_slow(t + 1);
        __syncthreads();
      }
    }
  }
  __syncthreads(); // staging region dead; phase-2 tiles take over

  // ---------------- write Q,K,V (bf16, swizzled) ----------------
  char* Qb = smem;
  char* Kb = smem + 16384;
  char* Vb = smem + 32768;
  char* Pb = smem;
#pragma unroll
  for (int mt = 0; mt < 2; ++mt) {
#pragma unroll
    for (int r = 0; r < 4; ++r) {
      int row = wv * 32 + mt * 16 + lg * 4 + r;
#pragma unroll
      for (int n = 0; n < 4; ++n) {
        *(ushort_t*)sptr(Kb, row, 128, (n * 16 + lr) * 2) = f2bf(acc[mt][n][r]);
        *(ushort_t*)sptr(Qb, row, 128, (n * 16 + lr) * 2) = f2bf(acc[mt][4 + n][r]);
      }
    }
    // V^T packed: 4 consecutive d-rows -> ds_write_b64
#pragma unroll
    for (int n = 0; n < 4; ++n) {
      short4v pk;
#pragma unroll
      for (int r = 0; r < 4; ++r) pk[r] = (short)f2bf(acc[mt][8 + n][r]);
      *(short4v*)sptr(Vb, n * 16 + lr, 256, (wv * 32 + mt * 16 + lg * 4) * 2) = pk;
    }
  }
  __syncthreads();

  // ---------------- QK^T ----------------
  f32x4 accw[2][8];
#pragma unroll
  for (int m = 0; m < 2; ++m)
#pragma unroll
    for (int n = 0; n < 8; ++n) accw[m][n] = (f32x4){0.f, 0.f, 0.f, 0.f};
#pragma unroll
  for (int ks = 0; ks < 2; ++ks) {
    bf16x8 a0 = *(const bf16x8*)sptr(Qb, wv * 32 + lr, 128, ks * 64 + lg * 16);
    bf16x8 a1 = *(const bf16x8*)sptr(Qb, wv * 32 + 16 + lr, 128, ks * 64 + lg * 16);
#pragma unroll
    for (int n = 0; n < 8; ++n) {
      bf16x8 b = *(const bf16x8*)sptr(Kb, n * 16 + lr, 128, ks * 64 + lg * 16);
      accw[0][n] = __builtin_amdgcn_mfma_f32_16x16x32_bf16(a0, b, accw[0][n], 0, 0, 0);
      accw[1][n] = __builtin_amdgcn_mfma_f32_16x16x32_bf16(a1, b, accw[1][n], 0, 0, 0);
    }
  }
  __syncthreads(); // all done reading Q/K before P overwrites

  // ---------------- softmax (wave-parallel over 16-lane col groups) ----------------
#pragma unroll
  for (int mt = 0; mt < 2; ++mt)
#pragma unroll
    for (int r = 0; r < 4; ++r) {
      float l[8];
      float m = -1e30f;
#pragma unroll
      for (int n = 0; n < 8; ++n) {
        float v = accw[mt][n][r] * 0.125f;
        if (n == 7 && lr >= 8) v = -1e30f; // col = 112+lr >= 120 masked
        l[n] = v;
        m = fmaxf(m, v);
      }
#pragma unroll
      for (int off = 1; off < 16; off <<= 1) m = fmaxf(m, __shfl_xor(m, off));
      float s = 0.f;
#pragma unroll
      for (int n = 0; n < 8; ++n) {
        float p = __expf(l[n] - m);
        l[n] = p;
        s += p;
      }
#pragma unroll
      for (int off = 1; off < 16; off <<= 1) s += __shfl_xor(s, off);
      float inv = 1.f / s;
      int row = wv * 32 + mt * 16 + lg * 4 + r;
#pragma unroll
      for (int n = 0; n < 8; ++n)
        *(ushort_t*)sptr(Pb, row, 256, (n * 16 + lr) * 2) = f2bf(l[n] * inv);
    }
  // no barrier: each wave reads only its own P rows; V covered by barrier above

  // ---------------- out = P @ V ----------------
  f32x4 acco[2][4];
#pragma unroll
  for (int m = 0; m < 2; ++m)
#pragma unroll
    for (int n = 0; n < 4; ++n) acco[m][n] = (f32x4){0.f, 0.f, 0.f, 0.f};
#pragma unroll
  for (int ks = 0; ks < 4; ++ks) {
    bf16x8 a0 = *(const bf16x8*)sptr(Pb, wv * 32 + lr, 256, ks * 64 + lg * 16);
    bf16x8 a1 = *(const bf16x8*)sptr(Pb, wv * 32 + 16 + lr, 256, ks * 64 + lg * 16);
#pragma unroll
    for (int n = 0; n < 4; ++n) {
      bf16x8 b = *(const bf16x8*)sptr(Vb, n * 16 + lr, 256, ks * 64 + lg * 16);
      acco[0][n] = __builtin_amdgcn_mfma_f32_16x16x32_bf16(a0, b, acco[0][n], 0, 0, 0);
      acco[1][n] = __builtin_amdgcn_mfma_f32_16x16x32_bf16(a1, b, acco[1][n], 0, 0, 0);
    }
  }

  // ---------------- epilogue: LDS transpose -> float4 coalesced stores ----------------
  __syncthreads(); // P/V dead
  float* Ob = (float*)smem; // [120][68] f32
#pragma unroll
  for (int mt = 0; mt < 2; ++mt)
#pragma unroll
    for (int r = 0; r < 4; ++r) {
      int row = wv * 32 + mt * 16 + lg * 4 + r;
      if (row < CC) {
#pragma unroll
        for (int n = 0; n < 4; ++n)
          Ob[row * 68 + n * 16 + lr] = acco[mt][n][r];
      }
    }
  __syncthreads();
  const size_t obase = (size_t)batch * CC * HH;
#pragma unroll
  for (int i = 0; i < 8; ++i) {
    int idx = i * 256 + tid; // float4 index, 1920 total
    if (idx < 1920) {
      int row = idx >> 4;
      int c4 = (idx & 15) * 4;
      f32x4 v = *(const f32x4*)(Ob + row * 68 + c4);
      *(f32x4*)(out + obase + (size_t)idx * 4) = v;
    }
  }
}

extern "C" void kernel_launch(void* const* d_in, const int* in_sizes, int n_in,
                              void* d_out, int out_size, void* d_ws, size_t ws_size,
                              hipStream_t stream) {
  (void)in_sizes; (void)n_in; (void)out_size;
  const float* x  = (const float*)d_in[0];
  const float* Wk = (const float*)d_in[1];
  const float* Wq = (const float*)d_in[2];
  const float* Wv = (const float*)d_in[3];
  float* out = (float*)d_out;
  if (ws_size >= (size_t)WIMG_BYTES && d_ws != nullptr) {
    ushort_t* wimg = (ushort_t*)d_ws;
    prep_w<<<480, 256, 0, stream>>>(Wk, Wq, Wv, wimg);
    fused_regional_head<true><<<NBATCH, 256, 0, stream>>>(x, Wk, Wq, Wv, wimg, out);
  } else {
    fused_regional_head<false><<<NBATCH, 256, 0, stream>>>(x, Wk, Wq, Wv, nullptr, out);
  }
}